// Round 5
// baseline (2396.543 us; speedup 1.0000x reference)
//
#include <hip/hip_runtime.h>

typedef short bf16x8 __attribute__((ext_vector_type(8)));
typedef float f32x4 __attribute__((ext_vector_type(4)));
typedef float f32x16 __attribute__((ext_vector_type(16)));

#define AS 264            // plain layout; 528B row stride => <=2-way LDS aliasing (free)
#define T0OFF (32 * AS)
#define T1OFF (64 * AS)

__device__ __forceinline__ unsigned short f2bf(float f) {      // RNE (pre-kernels only)
    union { float f; unsigned int u; } v; v.f = f;
    unsigned int u = v.u + 0x7FFFu + ((v.u >> 16) & 1u);
    return (unsigned short)(u >> 16);
}
// HW packed f32x2 -> bf16x2 (RNE), 1 VALU op. dst.lo = a, dst.hi = b.
__device__ __forceinline__ unsigned cvtpk(float a, float b) {
    unsigned r;
    asm("v_cvt_pk_bf16_f32 %0, %1, %2" : "=v"(r) : "v"(a), "v"(b));
    return r;
}
__device__ __forceinline__ float bf2f(unsigned int h) {
    union { unsigned int u; float f; } v; v.u = h << 16; return v.f;
}
__device__ __forceinline__ float sigm(float x) {
    return __builtin_amdgcn_rcpf(1.0f + __expf(-x));
}

struct f4s { float v[4]; };
__device__ __forceinline__ f4s ld4(const float* p) {
    float4 t = *(const float4*)p;
    f4s r; r.v[0] = t.x; r.v[1] = t.y; r.v[2] = t.z; r.v[3] = t.w; return r;
}

// ---------------- pre-kernels ----------------

__global__ void k_base(const float* __restrict__ ctx,
                       const float* __restrict__ w1,
                       const float* __restrict__ b1,
                       float* __restrict__ base) {
    const int b = blockIdx.x, n = threadIdx.x;
    float acc = b1[n];
    for (int c = 0; c < 128; ++c)
        acc += ctx[b * 128 + c] * w1[(3 + c) * 256 + n];
    base[b * 256 + n] = acc;
}

// 32x32x16 A-operand fragments: unit (kk,hb,lane) holds 8 bf16:
// wf[((kk*8+hb)*64+lane)*8 + j] = bf16( W[kk*16 + (lane>>5)*8 + j][hb*32 + (lane&31)] )
__global__ void k_frag(const float* __restrict__ w,
                       unsigned short* __restrict__ wf) {
    const int t = blockIdx.x * blockDim.x + threadIdx.x;  // 0..65535
    const int j = t & 7, lane = (t >> 3) & 63, hb = (t >> 9) & 7, kk = t >> 12;
    const int c = kk * 16 + (lane >> 5) * 8 + j;
    const int h = hb * 32 + (lane & 31);
    wf[t] = f2bf(w[c * 256 + h]);
}

// ---------------- gemm: 32x32x16, wave owns TWO hidden blocks (64 units) x 32 points ----
// Each LDS fragment read feeds 6 MFMAs.
// D[row=hidden hb*32 + (reg&3)+8*(reg>>2)+4*kh][col=point lane&31]
#define MFMA6(koff, w0, w1)                                                        \
    {                                                                              \
        const bf16x8 fP  = *(const bf16x8*)(Asl + abase + (koff));                 \
        const bf16x8 fT0 = *(const bf16x8*)(Asl + abase + (koff) + T0OFF);         \
        const bf16x8 fT1 = *(const bf16x8*)(Asl + abase + (koff) + T1OFF);         \
        aP0  = __builtin_amdgcn_mfma_f32_32x32x16_bf16(w0, fP,  aP0,  0, 0, 0);    \
        aT00 = __builtin_amdgcn_mfma_f32_32x32x16_bf16(w0, fT0, aT00, 0, 0, 0);    \
        aT10 = __builtin_amdgcn_mfma_f32_32x32x16_bf16(w0, fT1, aT10, 0, 0, 0);    \
        aP1  = __builtin_amdgcn_mfma_f32_32x32x16_bf16(w1, fP,  aP1,  0, 0, 0);    \
        aT01 = __builtin_amdgcn_mfma_f32_32x32x16_bf16(w1, fT0, aT01, 0, 0, 0);    \
        aT11 = __builtin_amdgcn_mfma_f32_32x32x16_bf16(w1, fT1, aT11, 0, 0, 0);    \
    }

// L2 epilogue: lane (p=lane&31, kh=lane>>5) holds, per g, hidden units
// hb*32 + 4*kh + 8*g + {0..3} of point p -> one 8B packed write per array per g.
__device__ __forceinline__ void el_write32(unsigned short* Asl,
                                           const f32x16& aP, const f32x16& aT0, const f32x16& aT1,
                                           int ebase) {   // ebase = p*AS + hb*32 + 4*kh
#pragma unroll
    for (int g = 0; g < 4; ++g) {
        float h[4], t0[4], t1[4];
#pragma unroll
        for (int e = 0; e < 4; ++e) {
            const float pre = aP[4 * g + e];        // bias already in acc
            const float s = sigm(pre);
            const float hv = pre * s;
            const float dd = fmaf(hv, 1.0f - s, s); // silu'(pre)
            h[e]  = hv;
            t0[e] = dd * aT0[4 * g + e];
            t1[e] = dd * aT1[4 * g + e];
        }
        uint2 v0, v1, v2;
        v0.x = cvtpk(h[0],  h[1]);  v0.y = cvtpk(h[2],  h[3]);
        v1.x = cvtpk(t0[0], t0[1]); v1.y = cvtpk(t0[2], t0[3]);
        v2.x = cvtpk(t1[0], t1[1]); v2.y = cvtpk(t1[2], t1[3]);
        *(uint2*)(Asl + ebase + 8 * g)         = v0;
        *(uint2*)(Asl + ebase + 8 * g + T0OFF) = v1;
        *(uint2*)(Asl + ebase + 8 * g + T1OFF) = v2;
    }
}

// ---------------- main kernel ----------------
// One WG = 32 points, 256 threads (4 waves), 2 WGs/CU -> 8 waves/CU.
// Wave w owns hidden blocks {2w, 2w+1} (64 units) x all 32 points.
// Layer 4 is fused into the layer-3 epilogue (pure registers, w4 reg-cached):
// no L3 el_write, no L4 LDS readback, no 12-step butterfly.
__launch_bounds__(256, 2)
__global__ void k_main(const float* __restrict__ x,
                       const float* __restrict__ w1,
                       const float* __restrict__ b2g,
                       const float* __restrict__ b3g,
                       const float* __restrict__ w4g,
                       const float* __restrict__ b4g,
                       const unsigned short* __restrict__ w2f,
                       const unsigned short* __restrict__ w3f,
                       const float* __restrict__ basep,
                       float* __restrict__ ldacc,
                       float* __restrict__ out) {
    __shared__ unsigned short Asl[96 * AS];    // [h;t0;t1] bf16, plain (32 rows each)
    __shared__ float w1r[3][256];
    __shared__ float basel[256];
    __shared__ float b2l[256], b3l[256];
    __shared__ float px[32][2];                // per-point position
    __shared__ float pslab[4][32][4];          // per-wave L4 partials (v0,v1,j00,j11)

    const int tid = threadIdx.x;
    const int wg = blockIdx.x;
    const int b = wg >> 7;                // 128 WGs per batch
    const int n0 = (wg & 127) << 5;       // 32 points per WG

    for (int i = tid; i < 768; i += 256) w1r[i >> 8][i & 255] = w1[i];
    basel[tid] = basep[b * 256 + tid];
    b2l[tid] = b2g[tid];
    b3l[tid] = b3g[tid];
    if (tid < 64) ((float*)px)[tid] = x[((b << 12) + n0) * 2 + tid];  // coalesced 32x(x0,x1)

    const int lane = tid & 63, wave = tid >> 6;
    const int p = lane & 31, kh = lane >> 5;
    const int hb0 = 2 * wave, hb1 = 2 * wave + 1;             // two hidden blocks per wave
    const int abase  = p * AS + kh * 8;                       // act-frag base (+kk*16)
    const int ebase0 = p * AS + hb0 * 32 + kh * 4;            // L2 el_write bases
    const int ebase1 = p * AS + hb1 * 32 + kh * 4;
    const int wub0   = hb0 * 64 + lane;                       // weight bf16x8-unit bases (+kk*512)
    const int wub1   = hb1 * 64 + lane;
    const int bbase0 = hb0 * 32 + kh * 4;                     // bias seed bases (+8*g)
    const int bbase1 = hb1 * 32 + kh * 4;

    const int p4 = tid >> 3;            // point (0..31) for L1
    const int ic = tid & 7;             // 8 threads per point, 32 hidden each

    // register-cached w4 for this lane's 32 hidden units (static indices -> VGPRs)
    float w4r0[32], w4r1[32];
#pragma unroll
    for (int hb = 0; hb < 2; ++hb)
#pragma unroll
        for (int g = 0; g < 4; ++g)
#pragma unroll
            for (int e = 0; e < 4; ++e) {
                const int hidden = (2 * wave + hb) * 32 + kh * 4 + 8 * g + e;
                w4r0[hb * 16 + g * 4 + e] = w4g[2 * hidden];
                w4r1[hb * 16 + g * 4 + e] = w4g[2 * hidden + 1];
            }

    const float b40 = b4g[0], b41 = b4g[1];
    float pldreg = 0.0f;                // live only in reducer lanes (tid<32)
    __syncthreads();

#pragma unroll 1
    for (int st = 0; st < 10; ++st) {
        const float ti = 0.1f * (float)st;
        // ---------- layer 1 ----------
        const float x0 = px[p4][0];
        const float x1 = px[p4][1];
#pragma unroll
        for (int g = 0; g < 8; ++g) {
            const int cb = g * 32 + (ic << 2);
            const f4s wa = ld4(&w1r[0][cb]);
            const f4s wb = ld4(&w1r[1][cb]);
            const f4s wc = ld4(&w1r[2][cb]);
            const f4s bs = ld4(&basel[cb]);
            float hf[4], t0f[4], t1f[4];
#pragma unroll
            for (int e = 0; e < 4; ++e) {
                const float pre = x0 * wa.v[e] + x1 * wb.v[e] + ti * wc.v[e] + bs.v[e];
                const float s = sigm(pre);
                const float h = pre * s;
                const float d = fmaf(h, 1.0f - s, s);
                hf[e]  = h;
                t0f[e] = d * wa.v[e];
                t1f[e] = d * wb.v[e];
            }
            uint2 v0, v1, v2;
            v0.x = cvtpk(hf[0],  hf[1]);  v0.y = cvtpk(hf[2],  hf[3]);
            v1.x = cvtpk(t0f[0], t0f[1]); v1.y = cvtpk(t0f[2], t0f[3]);
            v2.x = cvtpk(t1f[0], t1f[1]); v2.y = cvtpk(t1f[2], t1f[3]);
            *(uint2*)(Asl + p4 * AS + cb) = v0;
            *(uint2*)(Asl + T0OFF + p4 * AS + cb) = v1;
            *(uint2*)(Asl + T1OFF + p4 * AS + cb) = v2;
        }
        __syncthreads();                                      // (1) L1 writes visible

        // ---------- layer 2 ----------
        f32x16 aP0, aT00, aT10, aP1, aT01, aT11;
#pragma unroll
        for (int g = 0; g < 4; ++g) {
            const float4 bv0 = *(const float4*)&b2l[bbase0 + 8 * g];
            const float4 bv1 = *(const float4*)&b2l[bbase1 + 8 * g];
            aP0[4 * g + 0] = bv0.x; aP0[4 * g + 1] = bv0.y;
            aP0[4 * g + 2] = bv0.z; aP0[4 * g + 3] = bv0.w;
            aP1[4 * g + 0] = bv1.x; aP1[4 * g + 1] = bv1.y;
            aP1[4 * g + 2] = bv1.z; aP1[4 * g + 3] = bv1.w;
        }
#pragma unroll
        for (int r = 0; r < 16; ++r) { aT00[r] = 0.f; aT10[r] = 0.f; aT01[r] = 0.f; aT11[r] = 0.f; }
        {
            const bf16x8* __restrict__ wp = (const bf16x8*)w2f;
            bf16x8 b0[4], b1[4];
#pragma unroll
            for (int i = 0; i < 4; ++i) { b0[i] = wp[wub0 + i * 512]; b1[i] = wp[wub1 + i * 512]; }
#pragma unroll 1
            for (int kk = 0; kk < 12; kk += 4) {
#pragma unroll
                for (int u = 0; u < 4; ++u) {
                    MFMA6((kk + u) * 16, b0[u], b1[u]);
                    b0[u] = wp[wub0 + (kk + 4 + u) * 512];   // prefetch distance 4
                    b1[u] = wp[wub1 + (kk + 4 + u) * 512];
                }
            }
#pragma unroll
            for (int u = 0; u < 4; ++u) MFMA6((12 + u) * 16, b0[u], b1[u]);
        }
        __syncthreads();                                      // (2) all frag reads done
        el_write32(Asl, aP0, aT00, aT10, ebase0);
        el_write32(Asl, aP1, aT01, aT11, ebase1);
        __syncthreads();                                      // (3) L2 writes visible

        // ---------- layer 3 ----------
#pragma unroll
        for (int g = 0; g < 4; ++g) {
            const float4 bv0 = *(const float4*)&b3l[bbase0 + 8 * g];
            const float4 bv1 = *(const float4*)&b3l[bbase1 + 8 * g];
            aP0[4 * g + 0] = bv0.x; aP0[4 * g + 1] = bv0.y;
            aP0[4 * g + 2] = bv0.z; aP0[4 * g + 3] = bv0.w;
            aP1[4 * g + 0] = bv1.x; aP1[4 * g + 1] = bv1.y;
            aP1[4 * g + 2] = bv1.z; aP1[4 * g + 3] = bv1.w;
        }
#pragma unroll
        for (int r = 0; r < 16; ++r) { aT00[r] = 0.f; aT10[r] = 0.f; aT01[r] = 0.f; aT11[r] = 0.f; }
        {
            const bf16x8* __restrict__ wp = (const bf16x8*)w3f;
            bf16x8 b0[4], b1[4];
#pragma unroll
            for (int i = 0; i < 4; ++i) { b0[i] = wp[wub0 + i * 512]; b1[i] = wp[wub1 + i * 512]; }
#pragma unroll 1
            for (int kk = 0; kk < 12; kk += 4) {
#pragma unroll
                for (int u = 0; u < 4; ++u) {
                    MFMA6((kk + u) * 16, b0[u], b1[u]);
                    b0[u] = wp[wub0 + (kk + 4 + u) * 512];
                    b1[u] = wp[wub1 + (kk + 4 + u) * 512];
                }
            }
#pragma unroll
            for (int u = 0; u < 4; ++u) MFMA6((12 + u) * 16, b0[u], b1[u]);
        }

        // ---------- fused layer-3 epilogue + layer 4 (pure registers) ----------
        {
            float v0p = 0.f, v1p = 0.f, j00p = 0.f, j11p = 0.f;
#define EPI(AP, AT0, AT1, HB)                                                      \
            _Pragma("unroll")                                                      \
            for (int g = 0; g < 4; ++g) {                                          \
                _Pragma("unroll")                                                  \
                for (int e = 0; e < 4; ++e) {                                      \
                    const float pre = AP[4 * g + e];                               \
                    const float s = sigm(pre);                                     \
                    const float hv = pre * s;                                      \
                    const float dd = fmaf(hv, 1.0f - s, s);                        \
                    const float wA = w4r0[(HB) * 16 + g * 4 + e];                  \
                    const float wB = w4r1[(HB) * 16 + g * 4 + e];                  \
                    v0p  = fmaf(hv, wA, v0p);                                      \
                    v1p  = fmaf(hv, wB, v1p);                                      \
                    j00p = fmaf(dd * AT0[4 * g + e], wA, j00p);                    \
                    j11p = fmaf(dd * AT1[4 * g + e], wB, j11p);                    \
                }                                                                  \
            }
            EPI(aP0, aT00, aT10, 0)
            EPI(aP1, aT01, aT11, 1)
#undef EPI
            // combine the kh halves (lane p <-> lane p+32, same point)
            v0p  += __shfl_xor(v0p, 32);
            v1p  += __shfl_xor(v1p, 32);
            j00p += __shfl_xor(j00p, 32);
            j11p += __shfl_xor(j11p, 32);
            if (lane < 32) {
                float4 t; t.x = v0p; t.y = v1p; t.z = j00p; t.w = j11p;
                *(float4*)&pslab[wave][lane][0] = t;
            }
        }
        __syncthreads();                  // (4) pslab visible; all frag reads done

        // ---------- cross-wave reduce + point update ----------
        if (tid < 32) {
            const float4 a0 = *(const float4*)&pslab[0][tid][0];
            const float4 a1 = *(const float4*)&pslab[1][tid][0];
            const float4 a2 = *(const float4*)&pslab[2][tid][0];
            const float4 a3 = *(const float4*)&pslab[3][tid][0];
            const float v0 = a0.x + a1.x + a2.x + a3.x;
            const float v1 = a0.y + a1.y + a2.y + a3.y;
            const float dv = (a0.z + a1.z + a2.z + a3.z) + (a0.w + a1.w + a2.w + a3.w);
            px[tid][0] += 0.1f * (v0 + b40);
            px[tid][1] += 0.1f * (v1 + b41);
            pldreg     += 0.1f * dv;
        }
        __syncthreads();                  // (5) px update visible to next L1
    }

    // ---------- epilogue: FP32 output ----------
    if (tid < 32) {
        float2 o; o.x = px[tid][0]; o.y = px[tid][1];
        *(float2*)&out[((b << 12) + n0 + tid) * 2] = o;
#pragma unroll
        for (int o2 = 16; o2 > 0; o2 >>= 1) pldreg += __shfl_xor(pldreg, o2);
        if (tid == 0) atomicAdd(ldacc + b, pldreg);
    }
}

// copy 64 float accumulators -> fp32 logdet outputs
__global__ void k_fin(const float* __restrict__ ldacc, float* __restrict__ out) {
    out[524288 + threadIdx.x] = ldacc[threadIdx.x];
}

extern "C" void kernel_launch(void* const* d_in, const int* in_sizes, int n_in,
                              void* d_out, int out_size, void* d_ws, size_t ws_size,
                              hipStream_t stream) {
    const float* x   = (const float*)d_in[0];
    const float* ctx = (const float*)d_in[1];
    const float* w1  = (const float*)d_in[2];
    const float* b1  = (const float*)d_in[3];
    const float* w2  = (const float*)d_in[4];
    const float* b2  = (const float*)d_in[5];
    const float* w3  = (const float*)d_in[6];
    const float* b3  = (const float*)d_in[7];
    const float* w4  = (const float*)d_in[8];
    const float* b4  = (const float*)d_in[9];

    // d_ws layout: [0,128K) w2f bf16 | [128K,256K) w3f bf16 | [256K,320K) base fp32 | [320K,+256) ldacc
    char* ws = (char*)d_ws;
    unsigned short* w2f = (unsigned short*)ws;
    unsigned short* w3f = (unsigned short*)(ws + 131072);
    float* basep = (float*)(ws + 262144);
    float* ldacc = (float*)(ws + 327680);
    float* out = (float*)d_out;

    hipMemsetAsync(ldacc, 0, 64 * sizeof(float), stream);
    k_base<<<dim3(64), dim3(256), 0, stream>>>(ctx, w1, b1, basep);
    k_frag<<<dim3(128), dim3(512), 0, stream>>>(w2, w2f);
    k_frag<<<dim3(128), dim3(512), 0, stream>>>(w3, w3f);
    k_main<<<dim3(8192), dim3(256), 0, stream>>>(x, w1, b2, b3, w4, b4, w2f, w3f, basep, ldacc, out);
    k_fin<<<dim3(1), dim3(64), 0, stream>>>(ldacc, out);
}

// Round 6
// 2200.869 us; speedup vs baseline: 1.0889x; 1.0889x over previous
//
#include <hip/hip_runtime.h>

typedef short bf16x8 __attribute__((ext_vector_type(8)));
typedef float f32x4 __attribute__((ext_vector_type(4)));
typedef float f32x16 __attribute__((ext_vector_type(16)));

#define AS 264            // plain layout; 528B row stride => <=2-way LDS aliasing (free)
#define T0OFF (32 * AS)
#define T1OFF (64 * AS)

__device__ __forceinline__ unsigned short f2bf(float f) {      // RNE (pre-kernels only)
    union { float f; unsigned int u; } v; v.f = f;
    unsigned int u = v.u + 0x7FFFu + ((v.u >> 16) & 1u);
    return (unsigned short)(u >> 16);
}
// HW packed f32x2 -> bf16x2 (RNE), 1 VALU op. dst.lo = a, dst.hi = b.
__device__ __forceinline__ unsigned cvtpk(float a, float b) {
    unsigned r;
    asm("v_cvt_pk_bf16_f32 %0, %1, %2" : "=v"(r) : "v"(a), "v"(b));
    return r;
}
__device__ __forceinline__ float bf2f(unsigned int h) {
    union { unsigned int u; float f; } v; v.u = h << 16; return v.f;
}
__device__ __forceinline__ float sigm(float x) {
    return __builtin_amdgcn_rcpf(1.0f + __expf(-x));
}

struct f4s { float v[4]; };
__device__ __forceinline__ f4s ld4(const float* p) {
    float4 t = *(const float4*)p;
    f4s r; r.v[0] = t.x; r.v[1] = t.y; r.v[2] = t.z; r.v[3] = t.w; return r;
}

// ---------------- pre-kernels ----------------

__global__ void k_base(const float* __restrict__ ctx,
                       const float* __restrict__ w1,
                       const float* __restrict__ b1,
                       float* __restrict__ base) {
    const int b = blockIdx.x, n = threadIdx.x;
    float acc = b1[n];
    for (int c = 0; c < 128; ++c)
        acc += ctx[b * 128 + c] * w1[(3 + c) * 256 + n];
    base[b * 256 + n] = acc;
}

// 32x32x16 A-operand fragments: unit (kk,hb,lane) holds 8 bf16:
// wf[((kk*8+hb)*64+lane)*8 + j] = bf16( W[kk*16 + (lane>>5)*8 + j][hb*32 + (lane&31)] )
__global__ void k_frag(const float* __restrict__ w,
                       unsigned short* __restrict__ wf) {
    const int t = blockIdx.x * blockDim.x + threadIdx.x;  // 0..65535
    const int j = t & 7, lane = (t >> 3) & 63, hb = (t >> 9) & 7, kk = t >> 12;
    const int c = kk * 16 + (lane >> 5) * 8 + j;
    const int h = hb * 32 + (lane & 31);
    wf[t] = f2bf(w[c * 256 + h]);
}

// ---------------- gemm: 32x32x16, wave owns TWO hidden blocks (64 units) x 32 points ----
// Each LDS fragment read feeds 6 MFMAs.
// D[row=hidden hb*32 + (reg&3)+8*(reg>>2)+4*kh][col=point lane&31]
#define MFMA6(koff, w0, w1)                                                        \
    {                                                                              \
        const bf16x8 fP  = *(const bf16x8*)(Asl + abase + (koff));                 \
        const bf16x8 fT0 = *(const bf16x8*)(Asl + abase + (koff) + T0OFF);         \
        const bf16x8 fT1 = *(const bf16x8*)(Asl + abase + (koff) + T1OFF);         \
        aP0  = __builtin_amdgcn_mfma_f32_32x32x16_bf16(w0, fP,  aP0,  0, 0, 0);    \
        aT00 = __builtin_amdgcn_mfma_f32_32x32x16_bf16(w0, fT0, aT00, 0, 0, 0);    \
        aT10 = __builtin_amdgcn_mfma_f32_32x32x16_bf16(w0, fT1, aT10, 0, 0, 0);    \
        aP1  = __builtin_amdgcn_mfma_f32_32x32x16_bf16(w1, fP,  aP1,  0, 0, 0);    \
        aT01 = __builtin_amdgcn_mfma_f32_32x32x16_bf16(w1, fT0, aT01, 0, 0, 0);    \
        aT11 = __builtin_amdgcn_mfma_f32_32x32x16_bf16(w1, fT1, aT11, 0, 0, 0);    \
    }

// L2 epilogue: lane (p=lane&31, kh=lane>>5) holds, per g, hidden units
// hb*32 + 4*kh + 8*g + {0..3} of point p -> one 8B packed write per array per g.
__device__ __forceinline__ void el_write32(unsigned short* Asl,
                                           const f32x16& aP, const f32x16& aT0, const f32x16& aT1,
                                           int ebase) {   // ebase = p*AS + hb*32 + 4*kh
#pragma unroll
    for (int g = 0; g < 4; ++g) {
        float h[4], t0[4], t1[4];
#pragma unroll
        for (int e = 0; e < 4; ++e) {
            const float pre = aP[4 * g + e];        // bias already in acc
            const float s = sigm(pre);
            const float hv = pre * s;
            const float dd = fmaf(hv, 1.0f - s, s); // silu'(pre)
            h[e]  = hv;
            t0[e] = dd * aT0[4 * g + e];
            t1[e] = dd * aT1[4 * g + e];
        }
        uint2 v0, v1, v2;
        v0.x = cvtpk(h[0],  h[1]);  v0.y = cvtpk(h[2],  h[3]);
        v1.x = cvtpk(t0[0], t0[1]); v1.y = cvtpk(t0[2], t0[3]);
        v2.x = cvtpk(t1[0], t1[1]); v2.y = cvtpk(t1[2], t1[3]);
        *(uint2*)(Asl + ebase + 8 * g)         = v0;
        *(uint2*)(Asl + ebase + 8 * g + T0OFF) = v1;
        *(uint2*)(Asl + ebase + 8 * g + T1OFF) = v2;
    }
}

// ---------------- main kernel ----------------
// One WG = 32 points, 256 threads (4 waves), 2 WGs/CU -> 8 waves/CU.
// Wave w owns hidden blocks {2w, 2w+1} (64 units) x all 32 points.
// Layer 4 fused into the layer-3 epilogue; w4 read from LDS at use (broadcast,
// conflict-free) instead of a 64-reg cache (R5's spill source: 428 MB scratch).
__launch_bounds__(256, 2)
__global__ void k_main(const float* __restrict__ x,
                       const float* __restrict__ w1,
                       const float* __restrict__ b2g,
                       const float* __restrict__ b3g,
                       const float* __restrict__ w4g,
                       const float* __restrict__ b4g,
                       const unsigned short* __restrict__ w2f,
                       const unsigned short* __restrict__ w3f,
                       const float* __restrict__ basep,
                       float* __restrict__ ldacc,
                       float* __restrict__ out) {
    __shared__ unsigned short Asl[96 * AS];    // [h;t0;t1] bf16, plain (32 rows each)
    __shared__ float w1r[3][256];
    __shared__ float basel[256];
    __shared__ float b2l[256], b3l[256];
    __shared__ float w40l[256], w41l[256];
    __shared__ float px[32][2];                // per-point position
    __shared__ float pslab[4][32][4];          // per-wave L4 partials (v0,v1,j00,j11)

    const int tid = threadIdx.x;
    const int wg = blockIdx.x;
    const int b = wg >> 7;                // 128 WGs per batch
    const int n0 = (wg & 127) << 5;       // 32 points per WG

    for (int i = tid; i < 768; i += 256) w1r[i >> 8][i & 255] = w1[i];
    basel[tid] = basep[b * 256 + tid];
    b2l[tid]  = b2g[tid];
    b3l[tid]  = b3g[tid];
    w40l[tid] = w4g[2 * tid];
    w41l[tid] = w4g[2 * tid + 1];
    if (tid < 64) ((float*)px)[tid] = x[((b << 12) + n0) * 2 + tid];  // coalesced 32x(x0,x1)

    const int lane = tid & 63, wave = tid >> 6;
    const int p = lane & 31, kh = lane >> 5;
    const int hb0 = 2 * wave, hb1 = 2 * wave + 1;             // two hidden blocks per wave
    const int abase  = p * AS + kh * 8;                       // act-frag base (+kk*16)
    const int ebase0 = p * AS + hb0 * 32 + kh * 4;            // L2 el_write bases
    const int ebase1 = p * AS + hb1 * 32 + kh * 4;
    const int wub0   = hb0 * 64 + lane;                       // weight bf16x8-unit bases (+kk*512)
    const int wub1   = hb1 * 64 + lane;
    const int bbase0 = hb0 * 32 + kh * 4;                     // bias / w4 base (+8*g)
    const int bbase1 = hb1 * 32 + kh * 4;

    const int p4 = tid >> 3;            // point (0..31) for L1
    const int ic = tid & 7;             // 8 threads per point, 32 hidden each

    const float b40 = b4g[0], b41 = b4g[1];
    float pldreg = 0.0f;                // live only in reducer lanes (tid<32)
    __syncthreads();

#pragma unroll 1
    for (int st = 0; st < 10; ++st) {
        const float ti = 0.1f * (float)st;
        // ---------- layer 1 ----------
        const float x0 = px[p4][0];
        const float x1 = px[p4][1];
#pragma unroll
        for (int g = 0; g < 8; ++g) {
            const int cb = g * 32 + (ic << 2);
            const f4s wa = ld4(&w1r[0][cb]);
            const f4s wb = ld4(&w1r[1][cb]);
            const f4s wc = ld4(&w1r[2][cb]);
            const f4s bs = ld4(&basel[cb]);
            float hf[4], t0f[4], t1f[4];
#pragma unroll
            for (int e = 0; e < 4; ++e) {
                const float pre = x0 * wa.v[e] + x1 * wb.v[e] + ti * wc.v[e] + bs.v[e];
                const float s = sigm(pre);
                const float h = pre * s;
                const float d = fmaf(h, 1.0f - s, s);
                hf[e]  = h;
                t0f[e] = d * wa.v[e];
                t1f[e] = d * wb.v[e];
            }
            uint2 v0, v1, v2;
            v0.x = cvtpk(hf[0],  hf[1]);  v0.y = cvtpk(hf[2],  hf[3]);
            v1.x = cvtpk(t0f[0], t0f[1]); v1.y = cvtpk(t0f[2], t0f[3]);
            v2.x = cvtpk(t1f[0], t1f[1]); v2.y = cvtpk(t1f[2], t1f[3]);
            *(uint2*)(Asl + p4 * AS + cb) = v0;
            *(uint2*)(Asl + T0OFF + p4 * AS + cb) = v1;
            *(uint2*)(Asl + T1OFF + p4 * AS + cb) = v2;
        }
        __syncthreads();                                      // (1) L1 writes visible

        // ---------- layer 2 ----------
        f32x16 aP0, aT00, aT10, aP1, aT01, aT11;
#pragma unroll
        for (int g = 0; g < 4; ++g) {
            const float4 bv0 = *(const float4*)&b2l[bbase0 + 8 * g];
            const float4 bv1 = *(const float4*)&b2l[bbase1 + 8 * g];
            aP0[4 * g + 0] = bv0.x; aP0[4 * g + 1] = bv0.y;
            aP0[4 * g + 2] = bv0.z; aP0[4 * g + 3] = bv0.w;
            aP1[4 * g + 0] = bv1.x; aP1[4 * g + 1] = bv1.y;
            aP1[4 * g + 2] = bv1.z; aP1[4 * g + 3] = bv1.w;
        }
#pragma unroll
        for (int r = 0; r < 16; ++r) { aT00[r] = 0.f; aT10[r] = 0.f; aT01[r] = 0.f; aT11[r] = 0.f; }
        {
            const bf16x8* __restrict__ wp = (const bf16x8*)w2f;
            bf16x8 b0[4], b1[4];
#pragma unroll
            for (int i = 0; i < 4; ++i) { b0[i] = wp[wub0 + i * 512]; b1[i] = wp[wub1 + i * 512]; }
#pragma unroll 1
            for (int kk = 0; kk < 12; kk += 4) {
#pragma unroll
                for (int u = 0; u < 4; ++u) {
                    MFMA6((kk + u) * 16, b0[u], b1[u]);
                    b0[u] = wp[wub0 + (kk + 4 + u) * 512];   // prefetch distance 4
                    b1[u] = wp[wub1 + (kk + 4 + u) * 512];
                }
            }
#pragma unroll
            for (int u = 0; u < 4; ++u) MFMA6((12 + u) * 16, b0[u], b1[u]);
        }
        __syncthreads();                                      // (2) all frag reads done
        el_write32(Asl, aP0, aT00, aT10, ebase0);
        el_write32(Asl, aP1, aT01, aT11, ebase1);
        __syncthreads();                                      // (3) L2 writes visible

        // ---------- layer 3 ----------
#pragma unroll
        for (int g = 0; g < 4; ++g) {
            const float4 bv0 = *(const float4*)&b3l[bbase0 + 8 * g];
            const float4 bv1 = *(const float4*)&b3l[bbase1 + 8 * g];
            aP0[4 * g + 0] = bv0.x; aP0[4 * g + 1] = bv0.y;
            aP0[4 * g + 2] = bv0.z; aP0[4 * g + 3] = bv0.w;
            aP1[4 * g + 0] = bv1.x; aP1[4 * g + 1] = bv1.y;
            aP1[4 * g + 2] = bv1.z; aP1[4 * g + 3] = bv1.w;
        }
#pragma unroll
        for (int r = 0; r < 16; ++r) { aT00[r] = 0.f; aT10[r] = 0.f; aT01[r] = 0.f; aT11[r] = 0.f; }
        {
            const bf16x8* __restrict__ wp = (const bf16x8*)w3f;
            bf16x8 b0[4], b1[4];
#pragma unroll
            for (int i = 0; i < 4; ++i) { b0[i] = wp[wub0 + i * 512]; b1[i] = wp[wub1 + i * 512]; }
#pragma unroll 1
            for (int kk = 0; kk < 12; kk += 4) {
#pragma unroll
                for (int u = 0; u < 4; ++u) {
                    MFMA6((kk + u) * 16, b0[u], b1[u]);
                    b0[u] = wp[wub0 + (kk + 4 + u) * 512];
                    b1[u] = wp[wub1 + (kk + 4 + u) * 512];
                }
            }
#pragma unroll
            for (int u = 0; u < 4; ++u) MFMA6((12 + u) * 16, b0[u], b1[u]);
        }

        // ---------- fused layer-3 epilogue + layer 4 (w4 from LDS, broadcast) ----------
        {
            float v0p = 0.f, v1p = 0.f, j00p = 0.f, j11p = 0.f;
#define EPI(AP, AT0, AT1, BB)                                                      \
            _Pragma("unroll")                                                      \
            for (int g = 0; g < 4; ++g) {                                          \
                const f4s wA = ld4(&w40l[(BB) + 8 * g]);                           \
                const f4s wB = ld4(&w41l[(BB) + 8 * g]);                           \
                _Pragma("unroll")                                                  \
                for (int e = 0; e < 4; ++e) {                                      \
                    const float pre = AP[4 * g + e];                               \
                    const float s = sigm(pre);                                     \
                    const float hv = pre * s;                                      \
                    const float dd = fmaf(hv, 1.0f - s, s);                        \
                    v0p  = fmaf(hv, wA.v[e], v0p);                                 \
                    v1p  = fmaf(hv, wB.v[e], v1p);                                 \
                    j00p = fmaf(dd * AT0[4 * g + e], wA.v[e], j00p);               \
                    j11p = fmaf(dd * AT1[4 * g + e], wB.v[e], j11p);               \
                }                                                                  \
            }
            EPI(aP0, aT00, aT10, bbase0)
            EPI(aP1, aT01, aT11, bbase1)
#undef EPI
            // combine the kh halves (lane p <-> lane p+32, same point)
            v0p  += __shfl_xor(v0p, 32);
            v1p  += __shfl_xor(v1p, 32);
            j00p += __shfl_xor(j00p, 32);
            j11p += __shfl_xor(j11p, 32);
            if (lane < 32) {
                float4 t; t.x = v0p; t.y = v1p; t.z = j00p; t.w = j11p;
                *(float4*)&pslab[wave][lane][0] = t;
            }
        }
        __syncthreads();                  // (4) pslab visible; all frag reads done

        // ---------- cross-wave reduce + point update ----------
        if (tid < 32) {
            const float4 a0 = *(const float4*)&pslab[0][tid][0];
            const float4 a1 = *(const float4*)&pslab[1][tid][0];
            const float4 a2 = *(const float4*)&pslab[2][tid][0];
            const float4 a3 = *(const float4*)&pslab[3][tid][0];
            const float v0 = a0.x + a1.x + a2.x + a3.x;
            const float v1 = a0.y + a1.y + a2.y + a3.y;
            const float dv = (a0.z + a1.z + a2.z + a3.z) + (a0.w + a1.w + a2.w + a3.w);
            px[tid][0] += 0.1f * (v0 + b40);
            px[tid][1] += 0.1f * (v1 + b41);
            pldreg     += 0.1f * dv;
        }
        __syncthreads();                  // (5) px update visible to next L1
    }

    // ---------- epilogue: FP32 output ----------
    if (tid < 32) {
        float2 o; o.x = px[tid][0]; o.y = px[tid][1];
        *(float2*)&out[((b << 12) + n0 + tid) * 2] = o;
#pragma unroll
        for (int o2 = 16; o2 > 0; o2 >>= 1) pldreg += __shfl_xor(pldreg, o2);
        if (tid == 0) atomicAdd(ldacc + b, pldreg);
    }
}

// copy 64 float accumulators -> fp32 logdet outputs
__global__ void k_fin(const float* __restrict__ ldacc, float* __restrict__ out) {
    out[524288 + threadIdx.x] = ldacc[threadIdx.x];
}

extern "C" void kernel_launch(void* const* d_in, const int* in_sizes, int n_in,
                              void* d_out, int out_size, void* d_ws, size_t ws_size,
                              hipStream_t stream) {
    const float* x   = (const float*)d_in[0];
    const float* ctx = (const float*)d_in[1];
    const float* w1  = (const float*)d_in[2];
    const float* b1  = (const float*)d_in[3];
    const float* w2  = (const float*)d_in[4];
    const float* b2  = (const float*)d_in[5];
    const float* w3  = (const float*)d_in[6];
    const float* b3  = (const float*)d_in[7];
    const float* w4  = (const float*)d_in[8];
    const float* b4  = (const float*)d_in[9];

    // d_ws layout: [0,128K) w2f bf16 | [128K,256K) w3f bf16 | [256K,320K) base fp32 | [320K,+256) ldacc
    char* ws = (char*)d_ws;
    unsigned short* w2f = (unsigned short*)ws;
    unsigned short* w3f = (unsigned short*)(ws + 131072);
    float* basep = (float*)(ws + 262144);
    float* ldacc = (float*)(ws + 327680);
    float* out = (float*)d_out;

    hipMemsetAsync(ldacc, 0, 64 * sizeof(float), stream);
    k_base<<<dim3(64), dim3(256), 0, stream>>>(ctx, w1, b1, basep);
    k_frag<<<dim3(128), dim3(512), 0, stream>>>(w2, w2f);
    k_frag<<<dim3(128), dim3(512), 0, stream>>>(w3, w3f);
    k_main<<<dim3(8192), dim3(256), 0, stream>>>(x, w1, b2, b3, w4, b4, w2f, w3f, basep, ldacc, out);
    k_fin<<<dim3(1), dim3(64), 0, stream>>>(ldacc, out);
}

// Round 7
// 2189.284 us; speedup vs baseline: 1.0947x; 1.0053x over previous
//
#include <hip/hip_runtime.h>

typedef short bf16x8 __attribute__((ext_vector_type(8)));
typedef float f32x4 __attribute__((ext_vector_type(4)));

#define AS 264            // 528B row stride keeps frag reads at the b128 bank floor
#define T0OFF (16 * AS)
#define T1OFF (32 * AS)

__device__ __forceinline__ unsigned short f2bf(float f) {      // RNE (pre-kernels only)
    union { float f; unsigned int u; } v; v.f = f;
    unsigned int u = v.u + 0x7FFFu + ((v.u >> 16) & 1u);
    return (unsigned short)(u >> 16);
}
// HW packed f32x2 -> bf16x2 (RNE), 1 VALU op. dst.lo = a, dst.hi = b.
__device__ __forceinline__ unsigned cvtpk(float a, float b) {
    unsigned r;
    asm("v_cvt_pk_bf16_f32 %0, %1, %2" : "=v"(r) : "v"(a), "v"(b));
    return r;
}
__device__ __forceinline__ float sigm(float x) {
    return __builtin_amdgcn_rcpf(1.0f + __expf(-x));
}

struct f4s { float v[4]; };
__device__ __forceinline__ f4s ld4(const float* p) {
    float4 t = *(const float4*)p;
    f4s r; r.v[0] = t.x; r.v[1] = t.y; r.v[2] = t.z; r.v[3] = t.w; return r;
}

// ---------------- pre-kernels ----------------

__global__ void k_base(const float* __restrict__ ctx,
                       const float* __restrict__ w1,
                       const float* __restrict__ b1,
                       float* __restrict__ base) {
    const int b = blockIdx.x, n = threadIdx.x;
    float acc = b1[n];
    for (int c = 0; c < 128; ++c)
        acc += ctx[b * 128 + c] * w1[(3 + c) * 256 + n];
    base[b * 256 + n] = acc;
}

// 16x16x32 A-operand fragments (R1-verified layout):
// wf[((kk*4+q)*256+n)*8+j] = bf16(W[kk*32+q*8+j][n])
__global__ void k_frag(const float* __restrict__ w,
                       unsigned short* __restrict__ wf) {
    const int t = blockIdx.x * blockDim.x + threadIdx.x;  // 0..65535
    const int j = t & 7, n = (t >> 3) & 255, q = (t >> 11) & 3, kk = t >> 13;
    wf[t] = f2bf(w[(kk * 32 + q * 8 + j) * 256 + n]);
}

// ---------------- gemm: 16x16x32, swapped operands (A=weights, B=acts) ----------------
// D[row=hidden base0-col + q*4 + e][col=point m]; lane holds 4 consecutive hidden.
#define MFMA12(frag_base, buf)                                                             \
    {                                                                                      \
        const bf16x8 fP  = *(const bf16x8*)(Asl + (frag_base));                            \
        const bf16x8 fT0 = *(const bf16x8*)(Asl + (frag_base) + T0OFF);                    \
        const bf16x8 fT1 = *(const bf16x8*)(Asl + (frag_base) + T1OFF);                    \
        _Pragma("unroll")                                                                  \
        for (int nb = 0; nb < 4; ++nb) {                                                   \
            aP[nb]  = __builtin_amdgcn_mfma_f32_16x16x32_bf16(buf[nb], fP,  aP[nb],  0, 0, 0); \
            aT0[nb] = __builtin_amdgcn_mfma_f32_16x16x32_bf16(buf[nb], fT0, aT0[nb], 0, 0, 0); \
            aT1[nb] = __builtin_amdgcn_mfma_f32_16x16x32_bf16(buf[nb], fT1, aT1[nb], 0, 0, 0); \
        }                                                                                  \
    }

__device__ __forceinline__ void do_gemm_direct(const unsigned short* __restrict__ wf,
                                               const unsigned short* Asl,
                                               int raP, int base0,
                                               f32x4 aP[4], f32x4 aT0[4], f32x4 aT1[4]) {
    const bf16x8* __restrict__ wp = (const bf16x8*)wf;
    bf16x8 bufA[4], bufB[4];
#pragma unroll
    for (int nb = 0; nb < 4; ++nb) bufA[nb] = wp[base0 + nb * 16];
#pragma unroll 1
    for (int kk = 0; kk < 8; kk += 2) {
#pragma unroll
        for (int nb = 0; nb < 4; ++nb) bufB[nb] = wp[(kk + 1) * 1024 + base0 + nb * 16];
        MFMA12(raP + kk * 32, bufA);
        if (kk + 2 < 8) {
#pragma unroll
            for (int nb = 0; nb < 4; ++nb) bufA[nb] = wp[(kk + 2) * 1024 + base0 + nb * 16];
        }
        MFMA12(raP + (kk + 1) * 32, bufB);
    }
}

// L2 epilogue: lane (m,q) holds, per nb, hidden units wave*64+nb*16+q*4+{0..3}
// of point m -> one 8B packed write per array per nb.
__device__ __forceinline__ void el_write(unsigned short* Asl,
                                         const f32x4* aP, const f32x4* aT0, const f32x4* aT1,
                                         int ebase) {     // ebase = m*AS + wave*64 + q*4
#pragma unroll
    for (int nb = 0; nb < 4; ++nb) {
        float h[4], t0[4], t1[4];
#pragma unroll
        for (int e = 0; e < 4; ++e) {
            const float pre = aP[nb][e];            // bias already in acc
            const float s = sigm(pre);
            const float hv = pre * s;
            const float dd = fmaf(hv, 1.0f - s, s); // silu'(pre)
            h[e]  = hv;
            t0[e] = dd * aT0[nb][e];
            t1[e] = dd * aT1[nb][e];
        }
        uint2 v0, v1, v2;
        v0.x = cvtpk(h[0],  h[1]);  v0.y = cvtpk(h[2],  h[3]);
        v1.x = cvtpk(t0[0], t0[1]); v1.y = cvtpk(t0[2], t0[3]);
        v2.x = cvtpk(t1[0], t1[1]); v2.y = cvtpk(t1[2], t1[3]);
        *(uint2*)(Asl + ebase + nb * 16)         = v0;
        *(uint2*)(Asl + ebase + nb * 16 + T0OFF) = v1;
        *(uint2*)(Asl + ebase + nb * 16 + T1OFF) = v2;
    }
}

// ---------------- main kernel ----------------
// One WG = 16 points, 256 threads (4 waves), LDS ~34.7KB -> 4 WGs/CU = 4 waves/SIMD.
// Wave w owns hidden [w*64, w*64+64) x all 16 points (4 n-tiles, 16x16x32 MFMA).
// 4 independent barrier domains per CU: one WG's VALU phase overlaps another's GEMM.
__launch_bounds__(256, 4)
__global__ void k_main(const float* __restrict__ x,
                       const float* __restrict__ w1,
                       const float* __restrict__ b2g,
                       const float* __restrict__ b3g,
                       const float* __restrict__ w4g,
                       const float* __restrict__ b4g,
                       const unsigned short* __restrict__ w2f,
                       const unsigned short* __restrict__ w3f,
                       const float* __restrict__ basep,
                       float* __restrict__ ldacc,
                       float* __restrict__ out) {
    __shared__ unsigned short Asl[48 * AS];    // [h;t0;t1] bf16, 16 rows each
    __shared__ float w1r[3][256];
    __shared__ float basel[256];
    __shared__ float b2l[256], b3l[256];
    __shared__ float w40l[256], w41l[256];
    __shared__ float px[16][2];                // per-point position
    __shared__ float pslab[4][16][4];          // per-wave L4 partials (v0,v1,j00,j11)

    const int tid = threadIdx.x;
    const int wg = blockIdx.x;
    const int b = wg >> 8;                // 256 WGs per batch
    const int n0 = (wg & 255) << 4;       // 16 points per WG

    for (int i = tid; i < 768; i += 256) w1r[i >> 8][i & 255] = w1[i];
    basel[tid] = basep[b * 256 + tid];
    b2l[tid]  = b2g[tid];
    b3l[tid]  = b3g[tid];
    w40l[tid] = w4g[2 * tid];
    w41l[tid] = w4g[2 * tid + 1];
    if (tid < 32) ((float*)px)[tid] = x[((b << 12) + n0) * 2 + tid];  // 16x(x0,x1)

    const int lane = tid & 63, wave = tid >> 6;
    const int m = lane & 15, q = lane >> 4;
    const int raPq  = m * AS + q * 8;                         // act-frag base (+kk*32)
    const int ebase = m * AS + wave * 64 + (q << 2);          // el_write base
    const int base0 = q * 256 + wave * 64 + m;                // weight bf16x8-unit base
    const int bbase = wave * 64 + (q << 2);                   // bias / w4 base (+nb*16)

    const int p4 = tid >> 4;            // point (0..15) for L1
    const int ic = tid & 15;            // 16 threads per point, 16 hidden each

    const float b40 = b4g[0], b41 = b4g[1];
    float pldreg = 0.0f;                // live only in reducer lanes (tid<16)
    __syncthreads();

#pragma unroll 1
    for (int st = 0; st < 10; ++st) {
        const float ti = 0.1f * (float)st;
        // ---------- layer 1 (fused with prev step's L4; 16 hidden per thread) ----------
        const float x0 = px[p4][0];
        const float x1 = px[p4][1];
#pragma unroll
        for (int g = 0; g < 4; ++g) {
            const int cb = g * 64 + (ic << 2);
            const f4s wa = ld4(&w1r[0][cb]);
            const f4s wb = ld4(&w1r[1][cb]);
            const f4s wc = ld4(&w1r[2][cb]);
            const f4s bs = ld4(&basel[cb]);
            float hf[4], t0f[4], t1f[4];
#pragma unroll
            for (int e = 0; e < 4; ++e) {
                const float pre = x0 * wa.v[e] + x1 * wb.v[e] + ti * wc.v[e] + bs.v[e];
                const float s = sigm(pre);
                const float h = pre * s;
                const float d = fmaf(h, 1.0f - s, s);
                hf[e]  = h;
                t0f[e] = d * wa.v[e];
                t1f[e] = d * wb.v[e];
            }
            uint2 v0, v1, v2;
            v0.x = cvtpk(hf[0],  hf[1]);  v0.y = cvtpk(hf[2],  hf[3]);
            v1.x = cvtpk(t0f[0], t0f[1]); v1.y = cvtpk(t0f[2], t0f[3]);
            v2.x = cvtpk(t1f[0], t1f[1]); v2.y = cvtpk(t1f[2], t1f[3]);
            *(uint2*)(Asl + p4 * AS + cb) = v0;
            *(uint2*)(Asl + T0OFF + p4 * AS + cb) = v1;
            *(uint2*)(Asl + T1OFF + p4 * AS + cb) = v2;
        }
        __syncthreads();                                      // (1) L1 writes visible

        // ---------- layer 2 ----------
        f32x4 aP[4], aT0[4], aT1[4];
#pragma unroll
        for (int i = 0; i < 4; ++i) {
            const float4 bv = *(const float4*)&b2l[bbase + i * 16];  // broadcast read
            aP[i]  = f32x4{bv.x, bv.y, bv.z, bv.w};
            aT0[i] = f32x4{0.f, 0.f, 0.f, 0.f};
            aT1[i] = f32x4{0.f, 0.f, 0.f, 0.f};
        }
        do_gemm_direct(w2f, Asl, raPq, base0, aP, aT0, aT1);
        __syncthreads();                                      // (2) all frag reads done
        el_write(Asl, aP, aT0, aT1, ebase);
        __syncthreads();                                      // (3) L2 writes visible

        // ---------- layer 3 ----------
#pragma unroll
        for (int i = 0; i < 4; ++i) {
            const float4 bv = *(const float4*)&b3l[bbase + i * 16];
            aP[i]  = f32x4{bv.x, bv.y, bv.z, bv.w};
            aT0[i] = f32x4{0.f, 0.f, 0.f, 0.f};
            aT1[i] = f32x4{0.f, 0.f, 0.f, 0.f};
        }
        do_gemm_direct(w3f, Asl, raPq, base0, aP, aT0, aT1);

        // ---------- fused layer-3 epilogue + layer 4 (w4 from LDS, broadcast) ----------
        {
            float v0p = 0.f, v1p = 0.f, j00p = 0.f, j11p = 0.f;
#pragma unroll
            for (int nb = 0; nb < 4; ++nb) {
                const f4s wA = ld4(&w40l[bbase + nb * 16]);
                const f4s wB = ld4(&w41l[bbase + nb * 16]);
#pragma unroll
                for (int e = 0; e < 4; ++e) {
                    const float pre = aP[nb][e];
                    const float s = sigm(pre);
                    const float hv = pre * s;
                    const float dd = fmaf(hv, 1.0f - s, s);
                    v0p  = fmaf(hv, wA.v[e], v0p);
                    v1p  = fmaf(hv, wB.v[e], v1p);
                    j00p = fmaf(dd * aT0[nb][e], wA.v[e], j00p);
                    j11p = fmaf(dd * aT1[nb][e], wB.v[e], j11p);
                }
            }
            // combine the 4 q-groups (lanes m, m+16, m+32, m+48 share point m)
            v0p  += __shfl_xor(v0p, 16);  v0p  += __shfl_xor(v0p, 32);
            v1p  += __shfl_xor(v1p, 16);  v1p  += __shfl_xor(v1p, 32);
            j00p += __shfl_xor(j00p, 16); j00p += __shfl_xor(j00p, 32);
            j11p += __shfl_xor(j11p, 16); j11p += __shfl_xor(j11p, 32);
            if (lane < 16) {
                float4 t; t.x = v0p; t.y = v1p; t.z = j00p; t.w = j11p;
                *(float4*)&pslab[wave][m][0] = t;
            }
        }
        __syncthreads();                  // (4) pslab visible; all frag reads done

        // ---------- cross-wave reduce + point update ----------
        if (tid < 16) {
            const float4 a0 = *(const float4*)&pslab[0][tid][0];
            const float4 a1 = *(const float4*)&pslab[1][tid][0];
            const float4 a2 = *(const float4*)&pslab[2][tid][0];
            const float4 a3 = *(const float4*)&pslab[3][tid][0];
            const float v0 = a0.x + a1.x + a2.x + a3.x;
            const float v1 = a0.y + a1.y + a2.y + a3.y;
            const float dv = (a0.z + a1.z + a2.z + a3.z) + (a0.w + a1.w + a2.w + a3.w);
            px[tid][0] += 0.1f * (v0 + b40);
            px[tid][1] += 0.1f * (v1 + b41);
            pldreg     += 0.1f * dv;
        }
        __syncthreads();                  // (5) px update visible to next L1
    }

    // ---------- epilogue: FP32 output ----------
    if (tid < 16) {
        float2 o; o.x = px[tid][0]; o.y = px[tid][1];
        *(float2*)&out[((b << 12) + n0 + tid) * 2] = o;
#pragma unroll
        for (int o2 = 8; o2 > 0; o2 >>= 1) pldreg += __shfl_xor(pldreg, o2);
        if (tid == 0) atomicAdd(ldacc + b, pldreg);
    }
}

// copy 64 float accumulators -> fp32 logdet outputs
__global__ void k_fin(const float* __restrict__ ldacc, float* __restrict__ out) {
    out[524288 + threadIdx.x] = ldacc[threadIdx.x];
}

extern "C" void kernel_launch(void* const* d_in, const int* in_sizes, int n_in,
                              void* d_out, int out_size, void* d_ws, size_t ws_size,
                              hipStream_t stream) {
    const float* x   = (const float*)d_in[0];
    const float* ctx = (const float*)d_in[1];
    const float* w1  = (const float*)d_in[2];
    const float* b1  = (const float*)d_in[3];
    const float* w2  = (const float*)d_in[4];
    const float* b2  = (const float*)d_in[5];
    const float* w3  = (const float*)d_in[6];
    const float* b3  = (const float*)d_in[7];
    const float* w4  = (const float*)d_in[8];
    const float* b4  = (const float*)d_in[9];

    // d_ws layout: [0,128K) w2f bf16 | [128K,256K) w3f bf16 | [256K,320K) base fp32 | [320K,+256) ldacc
    char* ws = (char*)d_ws;
    unsigned short* w2f = (unsigned short*)ws;
    unsigned short* w3f = (unsigned short*)(ws + 131072);
    float* basep = (float*)(ws + 262144);
    float* ldacc = (float*)(ws + 327680);
    float* out = (float*)d_out;

    hipMemsetAsync(ldacc, 0, 64 * sizeof(float), stream);
    k_base<<<dim3(64), dim3(256), 0, stream>>>(ctx, w1, b1, basep);
    k_frag<<<dim3(128), dim3(512), 0, stream>>>(w2, w2f);
    k_frag<<<dim3(128), dim3(512), 0, stream>>>(w3, w3f);
    k_main<<<dim3(16384), dim3(256), 0, stream>>>(x, w1, b2, b3, w4, b4, w2f, w3f, basep, ldacc, out);
    k_fin<<<dim3(1), dim3(64), 0, stream>>>(ldacc, out);
}

// Round 9
// 2174.758 us; speedup vs baseline: 1.1020x; 1.0067x over previous
//
#include <hip/hip_runtime.h>

typedef short bf16x8 __attribute__((ext_vector_type(8)));
typedef float f32x4 __attribute__((ext_vector_type(4)));
typedef float f32x2 __attribute__((ext_vector_type(2)));

#define AS 264            // 528B row stride keeps frag reads at the b128 bank floor
#define T0OFF (16 * AS)
#define T1OFF (32 * AS)

__device__ __forceinline__ unsigned short f2bf(float f) {      // RNE (pre-kernels only)
    union { float f; unsigned int u; } v; v.f = f;
    unsigned int u = v.u + 0x7FFFu + ((v.u >> 16) & 1u);
    return (unsigned short)(u >> 16);
}
// HW packed f32x2 -> bf16x2 (RNE), 1 VALU op. dst.lo = a, dst.hi = b. (proven R2-R7)
__device__ __forceinline__ unsigned cvtpk(float a, float b) {
    unsigned r;
    asm("v_cvt_pk_bf16_f32 %0, %1, %2" : "=v"(r) : "v"(a), "v"(b));
    return r;
}

// pair silu via PLAIN VECTOR OPERATORS (no inline asm): LLVM may form v_pk_*_f32;
// worst case it scalarizes to R7's exact instruction stream. Transcendentals stay
// on the proven __expf / rcpf intrinsic path (compiler-managed hazards).
__device__ __forceinline__ void silu2v(f32x2 pre, f32x2& h, f32x2& d) {
    f32x2 e;
    e[0] = __expf(-pre[0]);
    e[1] = __expf(-pre[1]);
    f32x2 s;
    s[0] = __builtin_amdgcn_rcpf(1.0f + e[0]);
    s[1] = __builtin_amdgcn_rcpf(1.0f + e[1]);
    h = pre * s;
    d = h * (1.0f - s) + s;          // contracts to fma; scalar splats broadcast
}

struct f4s { float v[4]; };
__device__ __forceinline__ f4s ld4(const float* p) {
    float4 t = *(const float4*)p;
    f4s r; r.v[0] = t.x; r.v[1] = t.y; r.v[2] = t.z; r.v[3] = t.w; return r;
}

// ---------------- pre-kernels ----------------

__global__ void k_base(const float* __restrict__ ctx,
                       const float* __restrict__ w1,
                       const float* __restrict__ b1,
                       float* __restrict__ base) {
    const int b = blockIdx.x, n = threadIdx.x;
    float acc = b1[n];
    for (int c = 0; c < 128; ++c)
        acc += ctx[b * 128 + c] * w1[(3 + c) * 256 + n];
    base[b * 256 + n] = acc;
}

// 16x16x32 A-operand fragments (R1-verified layout):
// wf[((kk*4+q)*256+n)*8+j] = bf16(W[kk*32+q*8+j][n])
__global__ void k_frag(const float* __restrict__ w,
                       unsigned short* __restrict__ wf) {
    const int t = blockIdx.x * blockDim.x + threadIdx.x;  // 0..65535
    const int j = t & 7, n = (t >> 3) & 255, q = (t >> 11) & 3, kk = t >> 13;
    wf[t] = f2bf(w[(kk * 32 + q * 8 + j) * 256 + n]);
}

// ---------------- gemm: 16x16x32, swapped operands (A=weights, B=acts) ----------------
// D[row=hidden base0-col + q*4 + e][col=point m]; lane holds 4 consecutive hidden.
#define MFMA12(frag_base, buf)                                                             \
    {                                                                                      \
        const bf16x8 fP  = *(const bf16x8*)(Asl + (frag_base));                            \
        const bf16x8 fT0 = *(const bf16x8*)(Asl + (frag_base) + T0OFF);                    \
        const bf16x8 fT1 = *(const bf16x8*)(Asl + (frag_base) + T1OFF);                    \
        _Pragma("unroll")                                                                  \
        for (int nb = 0; nb < 4; ++nb) {                                                   \
            aP[nb]  = __builtin_amdgcn_mfma_f32_16x16x32_bf16(buf[nb], fP,  aP[nb],  0, 0, 0); \
            aT0[nb] = __builtin_amdgcn_mfma_f32_16x16x32_bf16(buf[nb], fT0, aT0[nb], 0, 0, 0); \
            aT1[nb] = __builtin_amdgcn_mfma_f32_16x16x32_bf16(buf[nb], fT1, aT1[nb], 0, 0, 0); \
        }                                                                                  \
    }

__device__ __forceinline__ void do_gemm_direct(const unsigned short* __restrict__ wf,
                                               const unsigned short* Asl,
                                               int raP, int base0,
                                               f32x4 aP[4], f32x4 aT0[4], f32x4 aT1[4]) {
    const bf16x8* __restrict__ wp = (const bf16x8*)wf;
    bf16x8 bufA[4], bufB[4];
#pragma unroll
    for (int nb = 0; nb < 4; ++nb) bufA[nb] = wp[base0 + nb * 16];
#pragma unroll 1
    for (int kk = 0; kk < 8; kk += 2) {
#pragma unroll
        for (int nb = 0; nb < 4; ++nb) bufB[nb] = wp[(kk + 1) * 1024 + base0 + nb * 16];
        MFMA12(raP + kk * 32, bufA);
        if (kk + 2 < 8) {
#pragma unroll
            for (int nb = 0; nb < 4; ++nb) bufA[nb] = wp[(kk + 2) * 1024 + base0 + nb * 16];
        }
        MFMA12(raP + (kk + 1) * 32, bufB);
    }
}

// L2 epilogue (pair-vector math): lane (m,q) holds, per nb, hidden units
// wave*64+nb*16+q*4+{0..3} of point m -> one 8B packed write per array per nb.
__device__ __forceinline__ void el_write(unsigned short* Asl,
                                         const f32x4* aP, const f32x4* aT0, const f32x4* aT1,
                                         int ebase) {     // ebase = m*AS + wave*64 + q*4
#pragma unroll
    for (int nb = 0; nb < 4; ++nb) {
        const f32x2 pA = {aP[nb][0], aP[nb][1]};
        const f32x2 pB = {aP[nb][2], aP[nb][3]};
        f32x2 hA, dA, hB, dB;
        silu2v(pA, hA, dA);
        silu2v(pB, hB, dB);
        const f32x2 t0A = dA * (f32x2){aT0[nb][0], aT0[nb][1]};
        const f32x2 t0B = dB * (f32x2){aT0[nb][2], aT0[nb][3]};
        const f32x2 t1A = dA * (f32x2){aT1[nb][0], aT1[nb][1]};
        const f32x2 t1B = dB * (f32x2){aT1[nb][2], aT1[nb][3]};
        uint2 v0, v1, v2;
        v0.x = cvtpk(hA[0], hA[1]);   v0.y = cvtpk(hB[0], hB[1]);
        v1.x = cvtpk(t0A[0], t0A[1]); v1.y = cvtpk(t0B[0], t0B[1]);
        v2.x = cvtpk(t1A[0], t1A[1]); v2.y = cvtpk(t1B[0], t1B[1]);
        *(uint2*)(Asl + ebase + nb * 16)         = v0;
        *(uint2*)(Asl + ebase + nb * 16 + T0OFF) = v1;
        *(uint2*)(Asl + ebase + nb * 16 + T1OFF) = v2;
    }
}

// ---------------- main kernel ----------------
// One WG = 16 points, 256 threads (4 waves), LDS ~34.7KB -> 4 WGs/CU = 4 waves/SIMD.
// Wave w owns hidden [w*64, w*64+64) x all 16 points (4 n-tiles, 16x16x32 MFMA).
// R7 skeleton; epilogue/L1 math expressed as f32x2 vector ops (compiler may pack).
__launch_bounds__(256, 4)
__global__ void k_main(const float* __restrict__ x,
                       const float* __restrict__ w1,
                       const float* __restrict__ b2g,
                       const float* __restrict__ b3g,
                       const float* __restrict__ w4g,
                       const float* __restrict__ b4g,
                       const unsigned short* __restrict__ w2f,
                       const unsigned short* __restrict__ w3f,
                       const float* __restrict__ basep,
                       float* __restrict__ ldacc,
                       float* __restrict__ out) {
    __shared__ unsigned short Asl[48 * AS];    // [h;t0;t1] bf16, 16 rows each
    __shared__ float w1r[3][256];
    __shared__ float basel[256];
    __shared__ float b2l[256], b3l[256];
    __shared__ float w40l[256], w41l[256];
    __shared__ float px[16][2];                // per-point position
    __shared__ float pslab[4][16][4];          // per-wave L4 partials (v0,v1,j00,j11)

    const int tid = threadIdx.x;
    const int wg = blockIdx.x;
    const int b = wg >> 8;                // 256 WGs per batch
    const int n0 = (wg & 255) << 4;       // 16 points per WG

    for (int i = tid; i < 768; i += 256) w1r[i >> 8][i & 255] = w1[i];
    basel[tid] = basep[b * 256 + tid];
    b2l[tid]  = b2g[tid];
    b3l[tid]  = b3g[tid];
    w40l[tid] = w4g[2 * tid];
    w41l[tid] = w4g[2 * tid + 1];
    if (tid < 32) ((float*)px)[tid] = x[((b << 12) + n0) * 2 + tid];  // 16x(x0,x1)

    const int lane = tid & 63, wave = tid >> 6;
    const int m = lane & 15, q = lane >> 4;
    const int raPq  = m * AS + q * 8;                         // act-frag base (+kk*32)
    const int ebase = m * AS + wave * 64 + (q << 2);          // el_write base
    const int base0 = q * 256 + wave * 64 + m;                // weight bf16x8-unit base
    const int bbase = wave * 64 + (q << 2);                   // bias / w4 base (+nb*16)

    const int p4 = tid >> 4;            // point (0..15) for L1
    const int ic = tid & 15;            // 16 threads per point, 16 hidden each

    const float b40 = b4g[0], b41 = b4g[1];
    float pldreg = 0.0f;                // live only in reducer lanes (tid<16)
    __syncthreads();

#pragma unroll 1
    for (int st = 0; st < 10; ++st) {
        const float ti = 0.1f * (float)st;
        // ---------- layer 1 (pair-vector math; same stores/indices as R7) ----------
        const float x0 = px[p4][0];
        const float x1 = px[p4][1];
        const f32x2 x02 = {x0, x0}, x12 = {x1, x1}, ti2 = {ti, ti};
#pragma unroll
        for (int g = 0; g < 4; ++g) {
            const int cb = g * 64 + (ic << 2);
            const f4s wa = ld4(&w1r[0][cb]);
            const f4s wb = ld4(&w1r[1][cb]);
            const f4s wc = ld4(&w1r[2][cb]);
            const f4s bs = ld4(&basel[cb]);
            const f32x2 wa0 = {wa.v[0], wa.v[1]}, wa1 = {wa.v[2], wa.v[3]};
            const f32x2 wb0 = {wb.v[0], wb.v[1]}, wb1 = {wb.v[2], wb.v[3]};
            const f32x2 wc0 = {wc.v[0], wc.v[1]}, wc1 = {wc.v[2], wc.v[3]};
            const f32x2 bs0 = {bs.v[0], bs.v[1]}, bs1 = {bs.v[2], bs.v[3]};
            const f32x2 pre0 = x02 * wa0 + x12 * wb0 + ti2 * wc0 + bs0;
            const f32x2 pre1 = x02 * wa1 + x12 * wb1 + ti2 * wc1 + bs1;
            f32x2 h0, d0, h1, d1;
            silu2v(pre0, h0, d0);
            silu2v(pre1, h1, d1);
            const f32x2 t00 = d0 * wa0, t01 = d1 * wa1;
            const f32x2 t10 = d0 * wb0, t11 = d1 * wb1;
            uint2 v0, v1, v2;
            v0.x = cvtpk(h0[0],  h0[1]);  v0.y = cvtpk(h1[0],  h1[1]);
            v1.x = cvtpk(t00[0], t00[1]); v1.y = cvtpk(t01[0], t01[1]);
            v2.x = cvtpk(t10[0], t10[1]); v2.y = cvtpk(t11[0], t11[1]);
            *(uint2*)(Asl + p4 * AS + cb) = v0;
            *(uint2*)(Asl + T0OFF + p4 * AS + cb) = v1;
            *(uint2*)(Asl + T1OFF + p4 * AS + cb) = v2;
        }
        __syncthreads();                                      // (1) L1 writes visible

        // ---------- layer 2 ----------
        f32x4 aP[4], aT0[4], aT1[4];
#pragma unroll
        for (int i = 0; i < 4; ++i) {
            const float4 bv = *(const float4*)&b2l[bbase + i * 16];  // broadcast read
            aP[i]  = f32x4{bv.x, bv.y, bv.z, bv.w};
            aT0[i] = f32x4{0.f, 0.f, 0.f, 0.f};
            aT1[i] = f32x4{0.f, 0.f, 0.f, 0.f};
        }
        do_gemm_direct(w2f, Asl, raPq, base0, aP, aT0, aT1);
        __syncthreads();                                      // (2) all frag reads done
        el_write(Asl, aP, aT0, aT1, ebase);
        __syncthreads();                                      // (3) L2 writes visible

        // ---------- layer 3 ----------
#pragma unroll
        for (int i = 0; i < 4; ++i) {
            const float4 bv = *(const float4*)&b3l[bbase + i * 16];
            aP[i]  = f32x4{bv.x, bv.y, bv.z, bv.w};
            aT0[i] = f32x4{0.f, 0.f, 0.f, 0.f};
            aT1[i] = f32x4{0.f, 0.f, 0.f, 0.f};
        }
        do_gemm_direct(w3f, Asl, raPq, base0, aP, aT0, aT1);

        // ---------- fused layer-3 epilogue + layer 4 (pair-vector, w4 from LDS) ----------
        {
            f32x2 v0a = {0.f, 0.f}, v1a = {0.f, 0.f}, j0a = {0.f, 0.f}, j1a = {0.f, 0.f};
#pragma unroll
            for (int nb = 0; nb < 4; ++nb) {
                const f4s wA = ld4(&w40l[bbase + nb * 16]);
                const f4s wB = ld4(&w41l[bbase + nb * 16]);
                const f32x2 wA0 = {wA.v[0], wA.v[1]}, wA1 = {wA.v[2], wA.v[3]};
                const f32x2 wB0 = {wB.v[0], wB.v[1]}, wB1 = {wB.v[2], wB.v[3]};
                const f32x2 pA = {aP[nb][0], aP[nb][1]};
                const f32x2 pB = {aP[nb][2], aP[nb][3]};
                f32x2 hA, dA, hB, dB;
                silu2v(pA, hA, dA);
                silu2v(pB, hB, dB);
                v0a = hA * wA0 + v0a; v0a = hB * wA1 + v0a;
                v1a = hA * wB0 + v1a; v1a = hB * wB1 + v1a;
                const f32x2 t0A = dA * (f32x2){aT0[nb][0], aT0[nb][1]};
                const f32x2 t0B = dB * (f32x2){aT0[nb][2], aT0[nb][3]};
                const f32x2 t1A = dA * (f32x2){aT1[nb][0], aT1[nb][1]};
                const f32x2 t1B = dB * (f32x2){aT1[nb][2], aT1[nb][3]};
                j0a = t0A * wA0 + j0a; j0a = t0B * wA1 + j0a;
                j1a = t1A * wB0 + j1a; j1a = t1B * wB1 + j1a;
            }
            float v0p  = v0a[0] + v0a[1];
            float v1p  = v1a[0] + v1a[1];
            float j00p = j0a[0] + j0a[1];
            float j11p = j1a[0] + j1a[1];
            // combine the 4 q-groups (lanes m, m+16, m+32, m+48 share point m)
            v0p  += __shfl_xor(v0p, 16);  v0p  += __shfl_xor(v0p, 32);
            v1p  += __shfl_xor(v1p, 16);  v1p  += __shfl_xor(v1p, 32);
            j00p += __shfl_xor(j00p, 16); j00p += __shfl_xor(j00p, 32);
            j11p += __shfl_xor(j11p, 16); j11p += __shfl_xor(j11p, 32);
            if (lane < 16) {
                float4 t; t.x = v0p; t.y = v1p; t.z = j00p; t.w = j11p;
                *(float4*)&pslab[wave][m][0] = t;
            }
        }
        __syncthreads();                  // (4) pslab visible; all frag reads done

        // ---------- cross-wave reduce + point update ----------
        if (tid < 16) {
            const float4 a0 = *(const float4*)&pslab[0][tid][0];
            const float4 a1 = *(const float4*)&pslab[1][tid][0];
            const float4 a2 = *(const float4*)&pslab[2][tid][0];
            const float4 a3 = *(const float4*)&pslab[3][tid][0];
            const float v0 = a0.x + a1.x + a2.x + a3.x;
            const float v1 = a0.y + a1.y + a2.y + a3.y;
            const float dv = (a0.z + a1.z + a2.z + a3.z) + (a0.w + a1.w + a2.w + a3.w);
            px[tid][0] += 0.1f * (v0 + b40);
            px[tid][1] += 0.1f * (v1 + b41);
            pldreg     += 0.1f * dv;
        }
        __syncthreads();                  // (5) px update visible to next L1
    }

    // ---------- epilogue: FP32 output ----------
    if (tid < 16) {
        float2 o; o.x = px[tid][0]; o.y = px[tid][1];
        *(float2*)&out[((b << 12) + n0 + tid) * 2] = o;
#pragma unroll
        for (int o2 = 8; o2 > 0; o2 >>= 1) pldreg += __shfl_xor(pldreg, o2);
        if (tid == 0) atomicAdd(ldacc + b, pldreg);
    }
}

// copy 64 float accumulators -> fp32 logdet outputs
__global__ void k_fin(const float* __restrict__ ldacc, float* __restrict__ out) {
    out[524288 + threadIdx.x] = ldacc[threadIdx.x];
}

extern "C" void kernel_launch(void* const* d_in, const int* in_sizes, int n_in,
                              void* d_out, int out_size, void* d_ws, size_t ws_size,
                              hipStream_t stream) {
    const float* x   = (const float*)d_in[0];
    const float* ctx = (const float*)d_in[1];
    const float* w1  = (const float*)d_in[2];
    const float* b1  = (const float*)d_in[3];
    const float* w2  = (const float*)d_in[4];
    const float* b2  = (const float*)d_in[5];
    const float* w3  = (const float*)d_in[6];
    const float* b3  = (const float*)d_in[7];
    const float* w4  = (const float*)d_in[8];
    const float* b4  = (const float*)d_in[9];

    // d_ws layout: [0,128K) w2f bf16 | [128K,256K) w3f bf16 | [256K,320K) base fp32 | [320K,+256) ldacc
    char* ws = (char*)d_ws;
    unsigned short* w2f = (unsigned short*)ws;
    unsigned short* w3f = (unsigned short*)(ws + 131072);
    float* basep = (float*)(ws + 262144);
    float* ldacc = (float*)(ws + 327680);
    float* out = (float*)d_out;

    hipMemsetAsync(ldacc, 0, 64 * sizeof(float), stream);
    k_base<<<dim3(64), dim3(256), 0, stream>>>(ctx, w1, b1, basep);
    k_frag<<<dim3(128), dim3(512), 0, stream>>>(w2, w2f);
    k_frag<<<dim3(128), dim3(512), 0, stream>>>(w3, w3f);
    k_main<<<dim3(16384), dim3(256), 0, stream>>>(x, w1, b2, b3, w4, b4, w2f, w3f, basep, ldacc, out);
    k_fin<<<dim3(1), dim3(64), 0, stream>>>(ldacc, out);
}